// Round 1
// baseline (236.663 us; speedup 1.0000x reference)
//
#include <hip/hip_runtime.h>

#define VOCAB 50257
#define EMBD  300
#define EMBP  320      // EMB padded to multiple of 32 for MFMA K
#define HID   1024
#define B3H   3072
#define BATCH 128
#define NBLK3 786      // ceil(50257/64)

typedef __attribute__((ext_vector_type(8))) short short8;
typedef __attribute__((ext_vector_type(4))) float f32x4;

__device__ __forceinline__ unsigned short f2bf(float f) {
  unsigned int u = __float_as_uint(f);
  u += 0x7fffu + ((u >> 16) & 1u);
  return (unsigned short)(u >> 16);
}

// ---------------- K0: gather + bf16 casts (x, h, w_ih, w_hh) ----------------
__global__ __launch_bounds__(256) void k0_prep(
    const int* __restrict__ ids, const float* __restrict__ emb,
    const float* __restrict__ hprev, const float* __restrict__ wih,
    const float* __restrict__ whh,
    unsigned short* __restrict__ xbf, unsigned short* __restrict__ hbf,
    unsigned short* __restrict__ wihbf, unsigned short* __restrict__ whhbf) {
  const int NX  = BATCH * EMBP;        // 40960
  const int NH  = BATCH * HID;         // 131072
  const int NWI = B3H * EMBP;          // 983040
  const int NWH = B3H * HID;           // 3145728
  const int total = NX + NH + NWI + NWH;
  for (int i = blockIdx.x * 256 + threadIdx.x; i < total; i += gridDim.x * 256) {
    if (i < NX) {
      int b = i / EMBP, k = i - b * EMBP;
      float f = (k < EMBD) ? emb[(size_t)ids[b] * EMBD + k] : 0.f;
      xbf[i] = f2bf(f);
    } else if (i < NX + NH) {
      int j = i - NX;
      hbf[j] = f2bf(hprev[j]);
    } else if (i < NX + NH + NWI) {
      int j = i - NX - NH;
      int n = j / EMBP, k = j - n * EMBP;
      wihbf[j] = f2bf((k < EMBD) ? wih[(size_t)n * EMBD + k] : 0.f);
    } else {
      int j = i - NX - NH - NWI;
      whhbf[j] = f2bf(whh[j]);
    }
  }
}

// ---------------- K1: gates GEMM (gi and gh), bf16 MFMA ----------------
// grid (48, 2): y=0 -> gi = x @ w_ih^T (K=320), y=1 -> gh = h @ w_hh^T (K=1024)
__global__ __launch_bounds__(256) void k1_gemm_gates(
    const unsigned short* __restrict__ xbf, const unsigned short* __restrict__ hbf,
    const unsigned short* __restrict__ wihbf, const unsigned short* __restrict__ whhbf,
    float* __restrict__ gi, float* __restrict__ gh) {
  const bool is_h = (blockIdx.y == 1);
  const unsigned short* A = is_h ? hbf : xbf;
  const unsigned short* B = is_h ? whhbf : wihbf;
  float* C = is_h ? gh : gi;
  const int K = is_h ? HID : EMBP;
  const int lane = threadIdx.x & 63;
  const int wid  = threadIdx.x >> 6;
  const int r = lane & 15, g = lane >> 4;
  const int nf = blockIdx.x * 64 + wid * 16;   // wave's 16-col n-base

  f32x4 acc[8];
#pragma unroll
  for (int i = 0; i < 8; i++) acc[i] = (f32x4){0.f, 0.f, 0.f, 0.f};

  for (int k0 = 0; k0 < K; k0 += 32) {
    short8 bfr = *(const short8*)(B + (size_t)(nf + r) * K + k0 + g * 8);
#pragma unroll
    for (int mi = 0; mi < 8; mi++) {
      short8 afr = *(const short8*)(A + (size_t)(mi * 16 + r) * K + k0 + g * 8);
      acc[mi] = __builtin_amdgcn_mfma_f32_16x16x32_bf16(afr, bfr, acc[mi], 0, 0, 0);
    }
  }
  // D layout: col = lane&15, row = (lane>>4)*4 + reg   [verified]
#pragma unroll
  for (int mi = 0; mi < 8; mi++)
#pragma unroll
    for (int rr = 0; rr < 4; rr++)
      C[(size_t)(mi * 16 + g * 4 + rr) * B3H + nf + r] = acc[mi][rr];
}

// ---------------- K2: elementwise GRU gates -> h_new (fp32 + bf16) ----------------
__global__ __launch_bounds__(256) void k2_gates(
    const float* __restrict__ gi, const float* __restrict__ gh,
    const float* __restrict__ bih, const float* __restrict__ bhh,
    const float* __restrict__ hprev,
    float* __restrict__ hnew_out, unsigned short* __restrict__ hnbf) {
  int i = blockIdx.x * 256 + threadIdx.x;     // 0..131071
  int b = i >> 10, j = i & 1023;
  size_t base = (size_t)b * B3H;
  float ir = gi[base + j]        + bih[j];
  float iz = gi[base + HID + j]  + bih[HID + j];
  float in_ = gi[base + 2*HID + j] + bih[2*HID + j];
  float hr = gh[base + j]        + bhh[j];
  float hz = gh[base + HID + j]  + bhh[HID + j];
  float hn = gh[base + 2*HID + j] + bhh[2*HID + j];
  float rg = 1.f / (1.f + expf(-(ir + hr)));
  float zg = 1.f / (1.f + expf(-(iz + hz)));
  float ng = tanhf(in_ + rg * hn);
  float h  = hprev[i];
  float hnew = (1.f - zg) * ng + zg * h;
  hnew_out[i] = hnew;
  hnbf[i] = f2bf(hnew);
}

// ---------------- K3: logits GEMM (bf16 MFMA, W_out cast in-flight) + partial max/sumexp ----
__global__ __launch_bounds__(256) void k3_logits(
    const unsigned short* __restrict__ Abf, const float* __restrict__ Wout,
    const float* __restrict__ bout, float* __restrict__ out,
    float2* __restrict__ part) {
  const int lane = threadIdx.x & 63;
  const int wid  = threadIdx.x >> 6;
  const int r = lane & 15, g = lane >> 4;
  const int v = blockIdx.x * 64 + wid * 16 + r;   // this lane's vocab column
  const bool vok = (v < VOCAB);

  f32x4 acc[8];
#pragma unroll
  for (int i = 0; i < 8; i++) acc[i] = (f32x4){0.f, 0.f, 0.f, 0.f};

  const float* brow = Wout + (size_t)v * HID;
  for (int k0 = 0; k0 < HID; k0 += 32) {
    short8 bfr = (short8){0,0,0,0,0,0,0,0};
    if (vok) {
      f32x4 w0 = *(const f32x4*)(brow + k0 + g * 8);
      f32x4 w1 = *(const f32x4*)(brow + k0 + g * 8 + 4);
      bfr[0] = (short)f2bf(w0[0]); bfr[1] = (short)f2bf(w0[1]);
      bfr[2] = (short)f2bf(w0[2]); bfr[3] = (short)f2bf(w0[3]);
      bfr[4] = (short)f2bf(w1[0]); bfr[5] = (short)f2bf(w1[1]);
      bfr[6] = (short)f2bf(w1[2]); bfr[7] = (short)f2bf(w1[3]);
    }
#pragma unroll
    for (int mi = 0; mi < 8; mi++) {
      short8 afr = *(const short8*)(Abf + (size_t)(mi * 16 + r) * HID + k0 + g * 8);
      acc[mi] = __builtin_amdgcn_mfma_f32_16x16x32_bf16(afr, bfr, acc[mi], 0, 0, 0);
    }
  }

  float bias = vok ? bout[v] : 0.f;
  __shared__ float tile[128][65];   // +1 pad; 33 KB
#pragma unroll
  for (int mi = 0; mi < 8; mi++)
#pragma unroll
    for (int rr = 0; rr < 4; rr++) {
      float val = acc[mi][rr] + bias;
      int b = mi * 16 + g * 4 + rr;
      if (vok) out[(size_t)b * VOCAB + v] = val;
      tile[b][wid * 16 + r] = vok ? val : -INFINITY;
    }
  __syncthreads();

  int t = threadIdx.x;
  if (t < 128) {
    float m = -INFINITY;
#pragma unroll 8
    for (int c = 0; c < 64; c++) m = fmaxf(m, tile[t][c]);
    float s = 0.f;
#pragma unroll 8
    for (int c = 0; c < 64; c++) s += __expf(tile[t][c] - m);
    part[(size_t)blockIdx.x * 128 + t] = make_float2(m, s);
  }
}

// ---------------- K4: combine per-block partials -> stat[b] = max + log(sumexp) ----------
__global__ __launch_bounds__(256) void k4_combine(
    const float2* __restrict__ part, float* __restrict__ stat) {
  int b = blockIdx.x, t = threadIdx.x;
  float2 p[4];
  int np = 0;
  float m = -INFINITY;
  for (int i = t; i < NBLK3; i += 256) {
    p[np] = part[(size_t)i * 128 + b];
    m = fmaxf(m, p[np].x);
    np++;
  }
  __shared__ float red[256];
  red[t] = m; __syncthreads();
  for (int s = 128; s > 0; s >>= 1) {
    if (t < s) red[t] = fmaxf(red[t], red[t + s]);
    __syncthreads();
  }
  float M = red[0]; __syncthreads();
  float ssum = 0.f;
  for (int i = 0; i < np; i++) ssum += p[i].y * __expf(p[i].x - M);
  red[t] = ssum; __syncthreads();
  for (int s = 128; s > 0; s >>= 1) {
    if (t < s) red[t] += red[t + s];
    __syncthreads();
  }
  if (t == 0) stat[b] = M + logf(red[0]);
}

// ---------------- K5: out = logit - stat[b] ----------------
__global__ __launch_bounds__(256) void k5_final(
    float* __restrict__ out, const float* __restrict__ stat) {
  int v = blockIdx.x * 256 + threadIdx.x;
  int b = blockIdx.y;
  if (v < VOCAB) {
    size_t i = (size_t)b * VOCAB + v;
    out[i] -= stat[b];
  }
}

extern "C" void kernel_launch(void* const* d_in, const int* in_sizes, int n_in,
                              void* d_out, int out_size, void* d_ws, size_t ws_size,
                              hipStream_t stream) {
  const int*   ids   = (const int*)  d_in[0];
  const float* hprev = (const float*)d_in[1];
  // d_in[2] = encoder_output, unused by the reference
  const float* emb   = (const float*)d_in[3];
  const float* wih   = (const float*)d_in[4];
  const float* whh   = (const float*)d_in[5];
  const float* bih   = (const float*)d_in[6];
  const float* bhh   = (const float*)d_in[7];
  const float* Wout  = (const float*)d_in[8];
  const float* bout  = (const float*)d_in[9];
  float* out = (float*)d_out;
  char* ws = (char*)d_ws;

  // ws layout (bytes, 256-aligned); total ~12.8 MB
  unsigned short* xbf   = (unsigned short*)(ws + 0);         // 128x320 bf16
  unsigned short* hbf   = (unsigned short*)(ws + 81920);     // 128x1024 bf16
  unsigned short* wihbf = (unsigned short*)(ws + 344064);    // 3072x320 bf16
  unsigned short* whhbf = (unsigned short*)(ws + 2310144);   // 3072x1024 bf16
  float*          gi    = (float*)(ws + 8601600);            // 128x3072 f32
  float*          gh    = (float*)(ws + 10174464);           // 128x3072 f32
  unsigned short* hnbf  = (unsigned short*)(ws + 11747328);  // 128x1024 bf16
  float2*         part  = (float2*)(ws + 12009472);          // 786x128 float2
  float*          stat  = (float*)(ws + 12814336);           // 128 f32

  float* hnew_out = out + (size_t)BATCH * VOCAB;

  hipLaunchKernelGGL(k0_prep, dim3(2048), dim3(256), 0, stream,
                     ids, emb, hprev, wih, whh, xbf, hbf, wihbf, whhbf);
  hipLaunchKernelGGL(k1_gemm_gates, dim3(48, 2), dim3(256), 0, stream,
                     xbf, hbf, wihbf, whhbf, gi, gh);
  hipLaunchKernelGGL(k2_gates, dim3(512), dim3(256), 0, stream,
                     gi, gh, bih, bhh, hprev, hnew_out, hnbf);
  hipLaunchKernelGGL(k3_logits, dim3(NBLK3), dim3(256), 0, stream,
                     hnbf, Wout, bout, out, part);
  hipLaunchKernelGGL(k4_combine, dim3(128), dim3(256), 0, stream, part, stat);
  hipLaunchKernelGGL(k5_final, dim3(197, 128), dim3(256), 0, stream, out, stat);
}

// Round 2
// 127.170 us; speedup vs baseline: 1.8610x; 1.8610x over previous
//
#include <hip/hip_runtime.h>

#define VOCAB 50257
#define EMBD  300
#define EMBP  320      // EMB padded to multiple of 32 for MFMA K
#define HID   1024
#define B3H   3072
#define BATCH 128
#define NBLK3 786      // ceil(50257/64)
#define NT    32       // K tiles of 32 in k3

typedef __attribute__((ext_vector_type(8))) short short8;
typedef __attribute__((ext_vector_type(4))) float f32x4;
typedef unsigned short ushort_t;

__device__ __forceinline__ unsigned short f2bf(float f) {
  unsigned int u = __float_as_uint(f);
  u += 0x7fffu + ((u >> 16) & 1u);
  return (unsigned short)(u >> 16);
}

__device__ __forceinline__ void gload16(const void* g, void* l) {
  __builtin_amdgcn_global_load_lds(
      (const __attribute__((address_space(1))) void*)g,
      (__attribute__((address_space(3))) void*)l, 16, 0, 0);
}

#define MEMF() asm volatile("" ::: "memory")

// ---------------- K0: gather + bf16 casts (x, h, w_ih) ----------------
__global__ __launch_bounds__(256) void k0_prep(
    const int* __restrict__ ids, const float* __restrict__ emb,
    const float* __restrict__ hprev, const float* __restrict__ wih,
    ushort_t* __restrict__ xbf, ushort_t* __restrict__ hbf,
    ushort_t* __restrict__ wihbf) {
  const int NX  = BATCH * EMBP;        // 40960
  const int NH  = BATCH * HID;         // 131072
  const int NWI = B3H * EMBP;          // 983040
  int i = blockIdx.x * 256 + threadIdx.x;   // grid covers NX+NH+NWI exactly
  if (i < NX) {
    int b = i / EMBP, k = i - b * EMBP;
    float f = (k < EMBD) ? emb[(size_t)ids[b] * EMBD + k] : 0.f;
    xbf[i] = f2bf(f);
  } else if (i < NX + NH) {
    int j = i - NX;
    hbf[j] = f2bf(hprev[j]);
  } else {
    int j = i - NX - NH;
    int n = j / EMBP, k = j - n * EMBP;
    wihbf[j] = f2bf((k < EMBD) ? wih[(size_t)n * EMBD + k] : 0.f);
  }
}

// ---------------- K1: gates GEMMs, 1 wave per block, 16 cols ----------------
// grid (192, 2): y=0 -> gi = x @ w_ih^T (K=320, bf16 B), y=1 -> gh = h @ w_hh^T (K=1024, fp32 B)
__global__ __launch_bounds__(64) void k1_gemm_gates(
    const ushort_t* __restrict__ xbf, const ushort_t* __restrict__ hbf,
    const ushort_t* __restrict__ wihbf, const float* __restrict__ whh,
    float* __restrict__ gi, float* __restrict__ gh) {
  const bool is_h = (blockIdx.y == 1);
  const int lane = threadIdx.x;
  const int r = lane & 15, g = lane >> 4;
  const int n = blockIdx.x * 16 + r;

  f32x4 acc[8];
#pragma unroll
  for (int i = 0; i < 8; i++) acc[i] = (f32x4){0.f, 0.f, 0.f, 0.f};

  if (is_h) {
    const float* brow = whh + (size_t)n * HID;
    for (int k0 = 0; k0 < HID; k0 += 32) {
      f32x4 wa = *(const f32x4*)(brow + k0 + g * 8);
      f32x4 wb = *(const f32x4*)(brow + k0 + g * 8 + 4);
      short8 bfr;
      bfr[0] = (short)f2bf(wa[0]); bfr[1] = (short)f2bf(wa[1]);
      bfr[2] = (short)f2bf(wa[2]); bfr[3] = (short)f2bf(wa[3]);
      bfr[4] = (short)f2bf(wb[0]); bfr[5] = (short)f2bf(wb[1]);
      bfr[6] = (short)f2bf(wb[2]); bfr[7] = (short)f2bf(wb[3]);
#pragma unroll
      for (int mi = 0; mi < 8; mi++) {
        short8 afr = *(const short8*)(hbf + (size_t)(mi * 16 + r) * HID + k0 + g * 8);
        acc[mi] = __builtin_amdgcn_mfma_f32_16x16x32_bf16(afr, bfr, acc[mi], 0, 0, 0);
      }
    }
  } else {
    const ushort_t* brow = wihbf + (size_t)n * EMBP;
    for (int k0 = 0; k0 < EMBP; k0 += 32) {
      short8 bfr = *(const short8*)(brow + k0 + g * 8);
#pragma unroll
      for (int mi = 0; mi < 8; mi++) {
        short8 afr = *(const short8*)(xbf + (size_t)(mi * 16 + r) * EMBP + k0 + g * 8);
        acc[mi] = __builtin_amdgcn_mfma_f32_16x16x32_bf16(afr, bfr, acc[mi], 0, 0, 0);
      }
    }
  }
  float* C = is_h ? gh : gi;
#pragma unroll
  for (int mi = 0; mi < 8; mi++)
#pragma unroll
    for (int rr = 0; rr < 4; rr++)
      C[(size_t)(mi * 16 + g * 4 + rr) * B3H + n] = acc[mi][rr];
}

// ---------------- K2: elementwise GRU gates -> h_new ----------------
__global__ __launch_bounds__(256) void k2_gates(
    const float* __restrict__ gi, const float* __restrict__ gh,
    const float* __restrict__ bih, const float* __restrict__ bhh,
    const float* __restrict__ hprev,
    float* __restrict__ hnew_out, ushort_t* __restrict__ hnbf) {
  int i = blockIdx.x * 256 + threadIdx.x;     // 0..131071
  int b = i >> 10, j = i & 1023;
  size_t base = (size_t)b * B3H;
  float ir = gi[base + j]          + bih[j];
  float iz = gi[base + HID + j]    + bih[HID + j];
  float in_ = gi[base + 2*HID + j] + bih[2*HID + j];
  float hr = gh[base + j]          + bhh[j];
  float hz = gh[base + HID + j]    + bhh[HID + j];
  float hn = gh[base + 2*HID + j]  + bhh[2*HID + j];
  float rg = 1.f / (1.f + expf(-(ir + hr)));
  float zg = 1.f / (1.f + expf(-(iz + hz)));
  float ng = tanhf(in_ + rg * hn);
  float h  = hprev[i];
  float hnew = (1.f - zg) * ng + zg * h;
  hnew_out[i] = hnew;
  hnbf[i] = f2bf(hnew);
}

// ---------------- K3: logits GEMM, LDS-staged, dbuf, counted vmcnt ----------------
// Block: 256 thr (4 waves), 64 vocab cols, K=1024 in NT=32 tiles of 32.
// LDS: Wt 64x32 f32 (chunk-XOR-swizzled), At 128x32 bf16 (linear), both x2 = 32 KB.
__global__ __launch_bounds__(256, 3) void k3_logits(
    const ushort_t* __restrict__ Abf, const float* __restrict__ Wout,
    const float* __restrict__ bout, float* __restrict__ out,
    float2* __restrict__ part) {
  __shared__ float    Wt[2][64 * 32];
  __shared__ ushort_t At[2][128 * 32];

  const int lane = threadIdx.x & 63;
  const int wid  = threadIdx.x >> 6;
  const int r = lane & 15, g = lane >> 4;
  const int vb = blockIdx.x * 64;

  // staging lane decomposition
  const int wsrow = lane >> 3;        // W: 8 rows / instr
  const int wschk = lane & 7;         // W: 8 16B-chunks / row
  const int asrow = lane >> 2;        // A: 16 rows / instr
  const int aschk = lane & 3;         // A: 4 16B-chunks / row

  f32x4 acc[8];
#pragma unroll
  for (int i = 0; i < 8; i++) acc[i] = (f32x4){0.f, 0.f, 0.f, 0.f};

  // ---- stage one k-tile (t) into buffer bf: 4 gload16 per wave ----
  // W: rows = tile vocab rows (clamped), source chunk pre-swizzled (rule 21)
  // A: linear both sides (row stride 64B already bank-uniform)
#define STAGE(T, BF)                                                          \
  {                                                                           \
    _Pragma("unroll")                                                         \
    for (int i = 0; i < 2; ++i) {                                             \
      int row = wid * 16 + i * 8 + wsrow;                                     \
      int vrow = vb + row; if (vrow > VOCAB - 1) vrow = VOCAB - 1;            \
      int chk = wschk ^ (row & 7);                                            \
      gload16(Wout + (size_t)vrow * HID + (T) * 32 + chk * 4,                 \
              &Wt[BF][(wid * 16 + i * 8) * 32]);                              \
    }                                                                         \
    _Pragma("unroll")                                                         \
    for (int i = 0; i < 2; ++i) {                                             \
      int row = wid * 32 + i * 16 + asrow;                                    \
      gload16(Abf + (size_t)row * HID + (T) * 32 + aschk * 8,                 \
              &At[BF][(wid * 32 + i * 16) * 32]);                             \
    }                                                                         \
  }

  STAGE(0, 0);

  for (int t = 0; t < NT; ++t) {
    const int cb = t & 1;
    MEMF(); __builtin_amdgcn_s_barrier(); MEMF();   // readers of sb done
    if (t + 1 < NT) {
      STAGE(t + 1, cb ^ 1);
      asm volatile("s_waitcnt vmcnt(4)" ::: "memory");  // cur tile's 4 staged loads done
    } else {
      asm volatile("s_waitcnt vmcnt(0)" ::: "memory");
    }
    MEMF(); __builtin_amdgcn_s_barrier(); MEMF();   // cur tile visible to all waves

    // W fragment: floats g*8..g*8+8 of row wid*16+r, via swizzled chunks
    const float* wrow = &Wt[cb][(wid * 16 + r) * 32];
    const int sw = r & 7;
    f32x4 wa = *(const f32x4*)(wrow + (((g << 1)    ) ^ sw) * 4);
    f32x4 wb = *(const f32x4*)(wrow + (((g << 1) | 1) ^ sw) * 4);
    short8 bfr;
    bfr[0] = (short)f2bf(wa[0]); bfr[1] = (short)f2bf(wa[1]);
    bfr[2] = (short)f2bf(wa[2]); bfr[3] = (short)f2bf(wa[3]);
    bfr[4] = (short)f2bf(wb[0]); bfr[5] = (short)f2bf(wb[1]);
    bfr[6] = (short)f2bf(wb[2]); bfr[7] = (short)f2bf(wb[3]);
#pragma unroll
    for (int mi = 0; mi < 8; ++mi) {
      short8 afr = *(const short8*)&At[cb][(mi * 16 + r) * 32 + g * 8];
      acc[mi] = __builtin_amdgcn_mfma_f32_16x16x32_bf16(afr, bfr, acc[mi], 0, 0, 0);
    }
  }
#undef STAGE

  // ---- epilogue: bias, store logits, wave-parallel softmax partials ----
  const int v = vb + wid * 16 + r;
  const bool vok = (v < VOCAB);
  float bias = bout[vok ? v : VOCAB - 1];
#pragma unroll
  for (int mi = 0; mi < 8; ++mi) {
#pragma unroll
    for (int rr = 0; rr < 4; ++rr) {
      float val = acc[mi][rr] + bias;
      int b = mi * 16 + g * 4 + rr;
      if (vok) out[(size_t)b * VOCAB + v] = val;
      float sv = vok ? val : -INFINITY;
      float m = sv;
      m = fmaxf(m, __shfl_xor(m, 1));
      m = fmaxf(m, __shfl_xor(m, 2));
      m = fmaxf(m, __shfl_xor(m, 4));
      m = fmaxf(m, __shfl_xor(m, 8));
      float s = vok ? __expf(sv - m) : 0.f;
      s += __shfl_xor(s, 1);
      s += __shfl_xor(s, 2);
      s += __shfl_xor(s, 4);
      s += __shfl_xor(s, 8);
      if (r == 0) part[((size_t)blockIdx.x * 4 + wid) * 128 + b] = make_float2(m, s);
    }
  }
}

// ---------------- K4: combine per-wave partials -> stat[b] ----------------
__global__ __launch_bounds__(256) void k4_combine(
    const float2* __restrict__ part, float* __restrict__ stat) {
  const int NP = NBLK3 * 4;   // 3144
  int b = blockIdx.x, t = threadIdx.x;
  float m = -INFINITY;
  for (int i = t; i < NP; i += 256) m = fmaxf(m, part[(size_t)i * 128 + b].x);
  __shared__ float red[256];
  red[t] = m; __syncthreads();
  for (int s = 128; s > 0; s >>= 1) {
    if (t < s) red[t] = fmaxf(red[t], red[t + s]);
    __syncthreads();
  }
  float M = red[0]; __syncthreads();
  float ssum = 0.f;
  for (int i = t; i < NP; i += 256) {
    float2 p = part[(size_t)i * 128 + b];
    ssum += p.y * __expf(p.x - M);
  }
  red[t] = ssum; __syncthreads();
  for (int s = 128; s > 0; s >>= 1) {
    if (t < s) red[t] += red[t + s];
    __syncthreads();
  }
  if (t == 0) stat[b] = M + logf(red[0]);
}

// ---------------- K5: out = logit - stat[b], float4 ----------------
__global__ __launch_bounds__(256) void k5_final(
    float* __restrict__ out, const float* __restrict__ stat) {
  const int total = BATCH * VOCAB;        // 6432896, divisible by 4
  int i4 = blockIdx.x * 256 + threadIdx.x;
  int base = i4 * 4;
  if (base >= total) return;
  float4 v = *(float4*)(out + base);
  int b0 = base / VOCAB, b3 = (base + 3) / VOCAB;
  if (b0 == b3) {
    float s = stat[b0];
    v.x -= s; v.y -= s; v.z -= s; v.w -= s;
  } else {
    v.x -= stat[base / VOCAB];
    v.y -= stat[(base + 1) / VOCAB];
    v.z -= stat[(base + 2) / VOCAB];
    v.w -= stat[(base + 3) / VOCAB];
  }
  *(float4*)(out + base) = v;
}

extern "C" void kernel_launch(void* const* d_in, const int* in_sizes, int n_in,
                              void* d_out, int out_size, void* d_ws, size_t ws_size,
                              hipStream_t stream) {
  const int*   ids   = (const int*)  d_in[0];
  const float* hprev = (const float*)d_in[1];
  // d_in[2] = encoder_output, unused by the reference
  const float* emb   = (const float*)d_in[3];
  const float* wih   = (const float*)d_in[4];
  const float* whh   = (const float*)d_in[5];
  const float* bih   = (const float*)d_in[6];
  const float* bhh   = (const float*)d_in[7];
  const float* Wout  = (const float*)d_in[8];
  const float* bout  = (const float*)d_in[9];
  float* out = (float*)d_out;
  char* ws = (char*)d_ws;

  // ws layout (bytes, 256-aligned); total ~8.94 MB
  ushort_t* xbf   = (ushort_t*)(ws + 0);         // 128x320 bf16
  ushort_t* hbf   = (ushort_t*)(ws + 81920);     // 128x1024 bf16
  ushort_t* wihbf = (ushort_t*)(ws + 344064);    // 3072x320 bf16
  float*    gi    = (float*)(ws + 2310144);      // 128x3072 f32
  float*    gh    = (float*)(ws + 3883008);      // 128x3072 f32
  ushort_t* hnbf  = (ushort_t*)(ws + 5455872);   // 128x1024 bf16
  float2*   part  = (float2*)(ws + 5718016);     // 3144x128 float2
  float*    stat  = (float*)(ws + 8937472);      // 128 f32

  float* hnew_out = out + (size_t)BATCH * VOCAB;

  hipLaunchKernelGGL(k0_prep, dim3(4512), dim3(256), 0, stream,
                     ids, emb, hprev, wih, xbf, hbf, wihbf);
  hipLaunchKernelGGL(k1_gemm_gates, dim3(192, 2), dim3(64), 0, stream,
                     xbf, hbf, wihbf, whh, gi, gh);
  hipLaunchKernelGGL(k2_gates, dim3(512), dim3(256), 0, stream,
                     gi, gh, bih, bhh, hprev, hnew_out, hnbf);
  hipLaunchKernelGGL(k3_logits, dim3(NBLK3), dim3(256), 0, stream,
                     hnbf, Wout, bout, out, part);
  hipLaunchKernelGGL(k4_combine, dim3(128), dim3(256), 0, stream, part, stat);
  hipLaunchKernelGGL(k5_final, dim3((BATCH * VOCAB / 4 + 255) / 256), dim3(256), 0, stream,
                     out, stat);
}